// Round 2
// baseline (228.479 us; speedup 1.0000x reference)
//
#include <hip/hip_runtime.h>

// HardPartPyramidPooling: x(16,256,32,16,11) fp32, labels(16,32,176) int,
// out(16,256,32,16) fp32.  out[n][c][s][p] = sum/cnt + max (0 if cnt==0).
// Memory-bound: ~101 MB traffic, HBM floor ~16 us.
//
// R2: replace serialized LDS read-modify-write (latency chain, ~120cyc/op)
// with fire-and-forget LDS atomics: ds_add_f32 for sum, ds_max_u32 on a
// monotone float->uint encoding for max. No lgkmcnt chains. Atomics also let
// 2 hw-halves share one accumulator set -> LDS 33.6 KB, 16 waves/CU.

constexpr int C  = 256;
constexpr int S  = 32;
constexpr int HW = 176;   // 16*11
constexpr int P  = 16;

// monotone float->uint: f1<f2  <=>  enc(f1)<enc(f2) (unsigned)
__device__ __forceinline__ unsigned enc(float f) {
    int b = __float_as_int(f);
    return (unsigned)(b ^ ((b >> 31) | 0x80000000));
}
__device__ __forceinline__ float dec(unsigned u) {
    int b = (u & 0x80000000u) ? (int)(u ^ 0x80000000u) : ~(int)u;
    return __int_as_float(b);
}

// block = 512 threads: tid&255 = channel, tid>>8 = hw-half (88 elems each)
__global__ __launch_bounds__(512, 4) void hpp_kernel(
    const float* __restrict__ x,
    const int*   __restrict__ labels,
    float*       __restrict__ out)
{
    __shared__ float    s_sum[P * C];   // 16 KB, word idx % 32 == c % 32
    __shared__ unsigned s_max[P * C];   // 16 KB (encoded)
    __shared__ int      s_lbl[HW];
    __shared__ int      s_cnt[P];

    const int tid = threadIdx.x;
    const int blk = blockIdx.x;        // n*S + s
    const int n   = blk >> 5;
    const int s   = blk & (S - 1);
    const int c   = tid & (C - 1);
    const int h2  = tid >> 8;          // 0 or 1

    // init accumulators (vectorized): 2 * 4096 words / 512 threads
    {
        float4* ps = (float4*)s_sum;
        uint4*  pm = (uint4*)s_max;
        ps[tid]        = make_float4(0.f, 0.f, 0.f, 0.f);
        ps[tid + 512]  = make_float4(0.f, 0.f, 0.f, 0.f);
        pm[tid]        = make_uint4(0u, 0u, 0u, 0u);   // enc-min
        pm[tid + 512]  = make_uint4(0u, 0u, 0u, 0u);
        if (tid < P) s_cnt[tid] = 0;
    }
    __syncthreads();

    if (tid < HW) {
        int l = labels[blk * HW + tid];
        s_lbl[tid] = l;
        atomicAdd(&s_cnt[l], 1);
    }
    __syncthreads();

    // per-lane sequential float4 walk of this channel's half-row (352 B)
    const float4* __restrict__ row =
        (const float4*)(x + ((((size_t)n * C + c) * S + s) * HW)) + h2 * 22;
    const int ebase = h2 * 88;

    #pragma unroll 2
    for (int v = 0; v < 22; ++v) {
        float4 val = row[v];
        int base = ebase + v * 4;
        int l0 = s_lbl[base + 0];   // wave-uniform -> LDS broadcast
        int l1 = s_lbl[base + 1];
        int l2 = s_lbl[base + 2];
        int l3 = s_lbl[base + 3];
        // fire-and-forget: ds_add_f32 / ds_max_u32, no dependency chain
        atomicAdd(&s_sum[(l0 << 8) + c], val.x);
        atomicMax(&s_max[(l0 << 8) + c], enc(val.x));
        atomicAdd(&s_sum[(l1 << 8) + c], val.y);
        atomicMax(&s_max[(l1 << 8) + c], enc(val.y));
        atomicAdd(&s_sum[(l2 << 8) + c], val.z);
        atomicMax(&s_max[(l2 << 8) + c], enc(val.z));
        atomicAdd(&s_sum[(l3 << 8) + c], val.w);
        atomicMax(&s_max[(l3 << 8) + c], enc(val.w));
    }
    __syncthreads();

    // epilogue: thread t -> channel t>>1, parts (t&1)*8 .. +8 ; 2x float4 store
    {
        const int ec = tid >> 1;
        const int p0 = (tid & 1) * 8;
        float res[8];
        #pragma unroll
        for (int j = 0; j < 8; ++j) {
            int   p   = p0 + j;
            int   cnt = s_cnt[p];
            float sum = s_sum[(p << 8) + ec];
            float mx  = dec(s_max[(p << 8) + ec]);
            res[j] = (cnt > 0) ? (sum / (float)cnt + mx) : 0.0f;
        }
        float4* o = (float4*)(out + ((((size_t)n * C + ec) * S + s) * P) + p0);
        o[0] = make_float4(res[0], res[1], res[2], res[3]);
        o[1] = make_float4(res[4], res[5], res[6], res[7]);
    }
}

extern "C" void kernel_launch(void* const* d_in, const int* in_sizes, int n_in,
                              void* d_out, int out_size, void* d_ws, size_t ws_size,
                              hipStream_t stream) {
    const float* x      = (const float*)d_in[0];
    const int*   labels = (const int*)d_in[1];
    float*       out    = (float*)d_out;

    const int ns = in_sizes[1] / HW;   // 512
    hpp_kernel<<<ns, 512, 0, stream>>>(x, labels, out);
}